// Round 6
// baseline (223.850 us; speedup 1.0000x reference)
//
#include <hip/hip_runtime.h>
#include <hip/hip_bf16.h>
#include <math.h>

#define C_DIM 1024
#define CR    256
#define A_N   10
#define NANCH 3
#define B_N   2
#define HW_N  4096
#define NTOK  (B_N*HW_N)   // 8192
#define KG2   (A_N*CR)     // 2560

typedef unsigned short ushort_t;
typedef __attribute__((ext_vector_type(4))) float f32x4;
typedef __attribute__((ext_vector_type(8))) short bf16x8;

__device__ __forceinline__ ushort_t f2bf(float x) {
    __hip_bfloat16 h = __float2bfloat16(x);
    return *reinterpret_cast<ushort_t*>(&h);
}

// tanh-form GELU via sigmoid identity; |err| < ~1e-3 (below bf16 rounding of G)
__device__ __forceinline__ float fast_gelu(float x) {
    float t = x * x;
    float u = x * (-1.5957691216f - 0.0713548163f * t);
    float e = __expf(u);
    return x * __frcp_rn(1.0f + e);
}

// ================= consolidated prep kernel =================
// blocks [0,640)    : w1t[a][d][c] = bf16(ln_scale[a][c]*w1[a][c][d])
// blocks [640,1280) : w2t[c][a*CR+d] = bf16(w2 flat [2560][1024] transposed)
// blocks [1280,2304): LN partial sums (atomic into zeroed sumv/sumq)
// blocks [2304,2464): bias1[a][d] += sum_c ln_bias[a][c]*w1[a][c][d] (atomic)
// blocks [2464,2496): wsel compaction — hierarchical (LDS counts, 10 global
//                     atomics/block; round-4's flat atomics cost 112 us)
// blocks [2496,5056): zero G (replaces 42 MB memset dispatch)
__global__ __launch_bounds__(256) void prep_all(
    const float* __restrict__ w1, const float* __restrict__ w2,
    const float* __restrict__ ln_s, const float* __restrict__ ln_b,
    const float* __restrict__ feat, const float* __restrict__ ar,
    ushort_t* __restrict__ w1t, ushort_t* __restrict__ w2t,
    float* __restrict__ bias1, float* __restrict__ sumv, float* __restrict__ sumq,
    int* __restrict__ cnt, int* __restrict__ tokw, ushort_t* __restrict__ G) {
    __shared__ float lds[64][65];
    __shared__ int lcnt[A_N], lpos[A_N], gbase[A_N];
    int id = blockIdx.x, tid = threadIdx.x;
    int lo = tid & 63, hi = tid >> 6;

    if (id < 640) {                       // ---- prep_w1t ----
        int d0 = (id & 3) * 64, c0 = ((id >> 2) & 15) * 64, a = id >> 6;
        #pragma unroll
        for (int i = 0; i < 16; i++) {
            int c_l = i * 4 + hi;
            lds[c_l][lo] = w1[((size_t)a * C_DIM + c0 + c_l) * CR + d0 + lo] * ln_s[a * C_DIM + c0 + c_l];
        }
        __syncthreads();
        #pragma unroll
        for (int i = 0; i < 16; i++) {
            int d_l = i * 4 + hi;
            w1t[((size_t)a * CR + d0 + d_l) * C_DIM + c0 + lo] = f2bf(lds[lo][d_l]);
        }
    } else if (id < 1280) {               // ---- prep_w2t ----
        int id2 = id - 640;
        int k0 = (id2 % 40) * 64, c0 = (id2 / 40) * 64;
        #pragma unroll
        for (int i = 0; i < 16; i++) {
            int k_l = i * 4 + hi;
            lds[k_l][lo] = w2[((size_t)k0 + k_l) * C_DIM + c0 + lo];
        }
        __syncthreads();
        #pragma unroll
        for (int i = 0; i < 16; i++) {
            int c_l = i * 4 + hi;
            w2t[((size_t)c0 + c_l) * KG2 + k0 + lo] = f2bf(lds[lo][c_l]);
        }
    } else if (id < 2304) {               // ---- ln partial sums ----
        int id2 = id - 1280;
        int p0 = (id2 & 63) * 64, c0 = ((id2 >> 6) & 7) * 128, b = id2 >> 9;
        int p = lo, cs = hi;
        float s = 0.f, s2 = 0.f;
        #pragma unroll
        for (int c = cs; c < 128; c += 4) {
            float v = feat[((size_t)b * C_DIM + c0 + c) * HW_N + p0 + p];
            s += v; s2 += v * v;
        }
        float (*sh)[64] = (float(*)[64])lds;
        sh[cs][p] = s; sh[cs + 4][p] = s2;
        __syncthreads();
        if (tid < 64) {
            float ss = sh[0][tid] + sh[1][tid] + sh[2][tid] + sh[3][tid];
            float qq = sh[4][tid] + sh[5][tid] + sh[6][tid] + sh[7][tid];
            int t = b * HW_N + p0 + tid;
            atomicAdd(&sumv[t], ss);
            atomicAdd(&sumq[t], qq);
        }
    } else if (id < 2464) {               // ---- bias1 ----
        int id3 = id - 2304;
        int c0 = (id3 & 15) * 64, a = id3 >> 4, d = tid;
        float s = 0.f;
        for (int c = c0; c < c0 + 64; c++)
            s += ln_b[a * C_DIM + c] * w1[((size_t)a * C_DIM + c) * CR + d];
        atomicAdd(&bias1[a * CR + d], s);
    } else if (id < 2496) {               // ---- wsel compaction (hierarchical) ----
        if (tid < A_N) { lcnt[tid] = 0; lpos[tid] = 0; }
        __syncthreads();
        int t = (id - 2464) * 256 + tid;  // < 8192
        int b = t >> 12, p = t & (HW_N - 1);
        const float THR[9] = {1.0f/9.0f, 1.0f/7.0f, 0.2f, 1.0f/3.0f, 1.0f, 3.0f, 5.0f, 7.0f, 9.0f};
        int idxs[NANCH];
        #pragma unroll
        for (int na = 0; na < NANCH; na++) {
            float v = ar[(size_t)b * NANCH * HW_N + na * HW_N + p];
            int idx = 0;
            #pragma unroll
            for (int i = 0; i < 9; i++) idx += (v > THR[i]) ? 1 : 0;
            idxs[na] = idx;
        }
        int myA[NANCH], myE[NANCH], nmine = 0;
        #pragma unroll
        for (int j = 0; j < NANCH; j++) {
            bool first = true; int c3 = 0;
            #pragma unroll
            for (int k = 0; k < NANCH; k++) {
                if (idxs[k] == idxs[j]) { c3++; if (k < j) first = false; }
            }
            if (first) {
                myA[nmine] = idxs[j];
                myE[nmine] = t | (c3 << 16);
                nmine++;
                atomicAdd(&lcnt[idxs[j]], 1);
            }
        }
        __syncthreads();
        if (tid < A_N) gbase[tid] = atomicAdd(&cnt[tid], lcnt[tid]);
        __syncthreads();
        for (int i = 0; i < nmine; i++) {
            int a2 = myA[i];
            int slot = atomicAdd(&lpos[a2], 1);
            tokw[a2 * NTOK + gbase[a2] + slot] = myE[i];
        }
    } else {                              // ---- zero G (16 KB / block) ----
        int gz = id - 2496;
        f32x4* dst = (f32x4*)(G + (size_t)gz * 8192);
        f32x4 z = {0.f, 0.f, 0.f, 0.f};
        #pragma unroll
        for (int i = 0; i < 4; i++) dst[tid * 4 + i] = z;
    }
}

// normG[t][c] = bf16((feat - mean)*rstd), token-major; finalizes LN stats inline
__global__ __launch_bounds__(256) void normk(const float* __restrict__ feat,
                                             const float* __restrict__ sumv,
                                             const float* __restrict__ sumq,
                                             ushort_t* __restrict__ normG) {
    int p0 = blockIdx.x * 64, c0 = blockIdx.y * 64, b = blockIdx.z;
    __shared__ float lds[64][65];
    int tid = threadIdx.x, lo = tid & 63, hi = tid >> 6;
    #pragma unroll
    for (int i = 0; i < 16; i++) {
        int c_l = i * 4 + hi;
        lds[c_l][lo] = feat[((size_t)b * C_DIM + c0 + c_l) * HW_N + p0 + lo];
    }
    __syncthreads();
    #pragma unroll
    for (int i = 0; i < 16; i++) {
        int p_l = i * 4 + hi;
        int t = b * HW_N + p0 + p_l;
        float m = sumv[t] * (1.f / C_DIM);
        float q = sumq[t] * (1.f / C_DIM);
        float r = rsqrtf(q - m * m + 1e-5f);
        normG[(size_t)t * C_DIM + c0 + lo] = f2bf((lds[lo][p_l] - m) * r);
    }
}

// ======== 128x128 bf16 MFMA core, pointer-parameterized (XOR-swizzled LDS) ========
__device__ __forceinline__ void gemm_core_ptrs(
    const ushort_t* const ap[4], const ushort_t* const bp[4],
    int K, ushort_t* As, ushort_t* Bs, f32x4 acc[4][4]) {
    const int tid = threadIdx.x;
    const int lane = tid & 63;
    const int w = tid >> 6;
    const int wr = w >> 1, wc = w & 1;
    const int lrow = lane & 15;
    const int quad = lane >> 4;
    const int swzr = lrow & 7;

    #pragma unroll
    for (int i = 0; i < 4; i++)
        #pragma unroll
        for (int j = 0; j < 4; j++)
            #pragma unroll
            for (int e = 0; e < 4; e++) acc[i][j][e] = 0.f;

    for (int k0 = 0; k0 < K; k0 += 64) {
        __syncthreads();
        #pragma unroll
        for (int i = 0; i < 4; i++) {
            __builtin_amdgcn_global_load_lds(
                (__attribute__((address_space(1))) void*)(ap[i] + k0),
                (__attribute__((address_space(3))) void*)(As + (w * 32 + i * 8) * 64),
                16, 0, 0);
            __builtin_amdgcn_global_load_lds(
                (__attribute__((address_space(1))) void*)(bp[i] + k0),
                (__attribute__((address_space(3))) void*)(Bs + (w * 32 + i * 8) * 64),
                16, 0, 0);
        }
        __syncthreads();
        #pragma unroll
        for (int ks = 0; ks < 2; ks++) {
            const int cidx = ((ks * 4 + quad) ^ swzr) * 8;
            bf16x8 af[4], bfr[4];
            #pragma unroll
            for (int mt = 0; mt < 4; mt++)
                af[mt] = *(const bf16x8*)(As + (wr * 64 + mt * 16 + lrow) * 64 + cidx);
            #pragma unroll
            for (int nt = 0; nt < 4; nt++)
                bfr[nt] = *(const bf16x8*)(Bs + (wc * 64 + nt * 16 + lrow) * 64 + cidx);
            #pragma unroll
            for (int mt = 0; mt < 4; mt++)
                #pragma unroll
                for (int nt = 0; nt < 4; nt++)
                    acc[mt][nt] = __builtin_amdgcn_mfma_f32_16x16x32_bf16(af[mt], bfr[nt], acc[mt][nt], 0, 0, 0);
        }
    }
}

// GEMM1 (compacted M): rows = tokens with wsel[a]>0 only. Writes into dense
// zero-filled G[t][a*256+d]; pad rows store-predicated, indices masked safe.
__global__ __launch_bounds__(256) void gemm1c(const ushort_t* __restrict__ normG,
                                              const ushort_t* __restrict__ w1t,
                                              const float* __restrict__ bias1,
                                              const int* __restrict__ tokw,
                                              const int* __restrict__ cnt,
                                              ushort_t* __restrict__ G) {
    int a = blockIdx.z;
    int mcount = cnt[a];
    int m0 = blockIdx.y * 128;
    if (m0 >= mcount) return;
    int n0 = blockIdx.x * 128;

    __shared__ __align__(16) ushort_t As[128 * 64];
    __shared__ __align__(16) ushort_t Bs[128 * 64];

    int tid = threadIdx.x, lane = tid & 63, w = tid >> 6;
    int lrow8 = lane >> 3;
    int scol = ((lane & 7) ^ lrow8) * 8;
    int srowl = w * 32 + lrow8;

    const ushort_t* ap[4];
    const ushort_t* bp[4];
    #pragma unroll
    for (int i = 0; i < 4; i++) {
        int rt = tokw[a * NTOK + m0 + srowl + i * 8] & (NTOK - 1);
        ap[i] = normG + (size_t)rt * C_DIM + scol;
        bp[i] = w1t + ((size_t)a * CR + n0 + srowl + i * 8) * C_DIM + scol;
    }

    f32x4 acc[4][4];
    gemm_core_ptrs(ap, bp, C_DIM, As, Bs, acc);

    int wr = w >> 1, wc = w & 1, lrow = lane & 15, quad = lane >> 4;
    float bi[4];
    #pragma unroll
    for (int nt = 0; nt < 4; nt++)
        bi[nt] = bias1[a * CR + n0 + wc * 64 + nt * 16 + lrow];
    #pragma unroll
    for (int mt = 0; mt < 4; mt++)
        #pragma unroll
        for (int r = 0; r < 4; r++) {
            int i_row = m0 + wr * 64 + mt * 16 + quad * 4 + r;
            int e = tokw[a * NTOK + i_row];
            int t = e & (NTOK - 1);
            float wv = (float)((e >> 16) & 3) * (1.0f / 3.0f);
            bool live = i_row < mcount;
            #pragma unroll
            for (int nt = 0; nt < 4; nt++) {
                int col = n0 + wc * 64 + nt * 16 + lrow;
                float v = acc[mt][nt][r] + bi[nt];
                if (live)
                    G[(size_t)t * KG2 + a * CR + col] = f2bf(fast_gelu(v) * wv);
            }
        }
}

// GEMM2: out[b][c][p] = (G @ W2stacked)[t][c] + feat[b][c][p], fused transpose+add.
// 1-D grid, XCD-aware: n-tile = f&7 == XCD (round-robin dispatch), so each XCD
// keeps its 0.65 MB w2t panel hot in L2 and all XCDs stream G m-panels in the
// same order (single pass through L3).
__global__ __launch_bounds__(256) void gemm2(const ushort_t* __restrict__ G,
                                             const ushort_t* __restrict__ w2t,
                                             const float* __restrict__ feat,
                                             float* __restrict__ out) {
    __shared__ __align__(16) char smem[32768];
    ushort_t* As = (ushort_t*)smem;
    ushort_t* Bs = (ushort_t*)(smem + 16384);
    float* tbuf = (float*)smem;
    int f = blockIdx.x;
    int n0 = (f & 7) * 128;
    int m0 = (f >> 3) * 128;

    int tid = threadIdx.x, lane = tid & 63, w = tid >> 6;
    int lrow8 = lane >> 3;
    int scol = ((lane & 7) ^ lrow8) * 8;
    int srowl = w * 32 + lrow8;

    const ushort_t* ap[4];
    const ushort_t* bp[4];
    #pragma unroll
    for (int i = 0; i < 4; i++) {
        ap[i] = G + (size_t)(m0 + srowl + i * 8) * KG2 + scol;
        bp[i] = w2t + (size_t)(n0 + srowl + i * 8) * KG2 + scol;
    }

    f32x4 acc[4][4];
    gemm_core_ptrs(ap, bp, KG2, As, Bs, acc);

    int wr = w >> 1, wc = w & 1, lrow = lane & 15, quad = lane >> 4;
    int b = m0 >> 12;
    int p_base = m0 & (HW_N - 1);
    #pragma unroll
    for (int cp = 0; cp < 4; cp++) {
        __syncthreads();
        int nh = cp - 2 * wc;
        if (nh == 0 || nh == 1) {
            #pragma unroll
            for (int nt2 = 0; nt2 < 2; nt2++) {
                int nt = nh * 2 + nt2;
                int cl = nt2 * 16 + lrow;
                #pragma unroll
                for (int mt = 0; mt < 4; mt++)
                    #pragma unroll
                    for (int r = 0; r < 4; r++) {
                        int rowl = wr * 64 + mt * 16 + quad * 4 + r;
                        tbuf[cl * 129 + rowl] = acc[mt][nt][r];
                    }
            }
        }
        __syncthreads();
        #pragma unroll
        for (int j = 0; j < 8; j++) {
            int c_idx = w * 8 + j;
            int c = n0 + cp * 32 + c_idx;
            #pragma unroll
            for (int h = 0; h < 2; h++) {
                int rowl = h * 64 + lane;
                size_t o = ((size_t)b * C_DIM + c) * HW_N + p_base + rowl;
                out[o] = tbuf[c_idx * 129 + rowl] + feat[o];
            }
        }
    }
}

// ---------------- launch ----------------
extern "C" void kernel_launch(void* const* d_in, const int* in_sizes, int n_in,
                              void* d_out, int out_size, void* d_ws, size_t ws_size,
                              hipStream_t stream) {
    (void)in_sizes; (void)n_in; (void)out_size; (void)ws_size;
    const float* feat = (const float*)d_in[0];
    const float* ar   = (const float*)d_in[1];
    const float* ln_s = (const float*)d_in[2];
    const float* ln_b = (const float*)d_in[3];
    const float* w1   = (const float*)d_in[4];
    const float* w2   = (const float*)d_in[5];
    float* out = (float*)d_out;
    char* ws = (char*)d_ws;

    // ---- zero-init region (one small memset: atomic targets only) ----
    float*    bias1 = (float*)(ws + 0);         // 10,240
    int*      cnt   = (int*)(ws + 10240);       // 40 (padded to 10496)
    float*    sumv  = (float*)(ws + 10496);     // 32,768
    float*    sumq  = (float*)(ws + 43264);     // 32,768
    ushort_t* G     = (ushort_t*)(ws + 76800);  // 41,943,040 (zeroed in prep_all)
    const size_t ZERO_BYTES = 76800;
    // ---- uninitialized region ----
    ushort_t* w1t   = (ushort_t*)(ws + 42019840); // 5,242,880
    ushort_t* w2t   = (ushort_t*)(ws + 47262720); // 5,242,880
    ushort_t* normG = (ushort_t*)(ws + 52505600); // 16,777,216
    int*      tokw  = (int*)(ws + 69282816);      // 327,680

    dim3 blk(256);
    hipMemsetAsync(ws, 0, ZERO_BYTES, stream);
    prep_all<<<dim3(5056), blk, 0, stream>>>(w1, w2, ln_s, ln_b, feat, ar,
                                             w1t, w2t, bias1, sumv, sumq, cnt, tokw, G);
    normk<<<dim3(64, 16, B_N), blk, 0, stream>>>(feat, sumv, sumq, normG);
    gemm1c<<<dim3(2, 64, A_N), blk, 0, stream>>>(normG, w1t, bias1, tokw, cnt, G);
    gemm2<<<dim3(512), blk, 0, stream>>>(G, w2t, feat, out);
}

// Round 8
// 191.614 us; speedup vs baseline: 1.1682x; 1.1682x over previous
//
#include <hip/hip_runtime.h>
#include <hip/hip_bf16.h>
#include <math.h>

#define C_DIM 1024
#define CR    256
#define A_N   10
#define NANCH 3
#define B_N   2
#define HW_N  4096
#define NTOK  (B_N*HW_N)   // 8192
#define KG2   (A_N*CR)     // 2560

typedef unsigned short ushort_t;
typedef __attribute__((ext_vector_type(4))) float f32x4;
typedef __attribute__((ext_vector_type(8))) short bf16x8;

__device__ __forceinline__ ushort_t f2bf(float x) {
    __hip_bfloat16 h = __float2bfloat16(x);
    return *reinterpret_cast<ushort_t*>(&h);
}
__device__ __forceinline__ float bf2f(ushort_t u) {
    return __uint_as_float(((unsigned)u) << 16);
}

// tanh-form GELU via sigmoid identity; |err| < ~1e-3 (below bf16 rounding)
__device__ __forceinline__ float fast_gelu(float x) {
    float t = x * x;
    float u = x * (-1.5957691216f - 0.0713548163f * t);
    float e = __expf(u);
    return x * __frcp_rn(1.0f + e);
}

// ================= consolidated prep kernel =================
// blocks [0,640)    : w1t[a][d][c] = bf16(ln_scale[a][c]*w1[a][c][d]) + fused
//                     bias1 partial (reuses the raw-w1 LDS tile)
// blocks [640,1280) : w2t[c][a*CR+d] = bf16(w2 flat [2560][1024] transposed)
// blocks [1280,2304): LN partial sums (atomic into zeroed sumv/sumq)
// blocks [2304,2336): wsel compaction (hierarchical LDS counts) + tokmap
__global__ __launch_bounds__(256) void prep_all(
    const float* __restrict__ w1, const float* __restrict__ w2,
    const float* __restrict__ ln_s, const float* __restrict__ ln_b,
    const float* __restrict__ feat, const float* __restrict__ ar,
    ushort_t* __restrict__ w1t, ushort_t* __restrict__ w2t,
    float* __restrict__ bias1, float* __restrict__ sumv, float* __restrict__ sumq,
    int* __restrict__ cnt, int* __restrict__ tokw, int* __restrict__ tokmap) {
    __shared__ float lds[64][65];
    __shared__ float bb[4][64];
    __shared__ int lcnt[A_N], lpos[A_N], gbase[A_N];
    int id = blockIdx.x, tid = threadIdx.x;
    int lo = tid & 63, hi = tid >> 6;

    if (id < 640) {                       // ---- prep_w1t + bias1 ----
        int d0 = (id & 3) * 64, c0 = ((id >> 2) & 15) * 64, a = id >> 6;
        #pragma unroll
        for (int i = 0; i < 16; i++) {
            int c_l = i * 4 + hi;
            lds[c_l][lo] = w1[((size_t)a * C_DIM + c0 + c_l) * CR + d0 + lo];  // raw
        }
        __syncthreads();
        // bias partial: thread owns d=lo, sums 16 c's
        {
            float s = 0.f;
            #pragma unroll
            for (int cc = 0; cc < 16; cc++) {
                int c = hi * 16 + cc;
                s += lds[c][lo] * ln_b[a * C_DIM + c0 + c];
            }
            bb[hi][lo] = s;
        }
        // scaled transpose store
        float sc = ln_s[a * C_DIM + c0 + lo];
        #pragma unroll
        for (int i = 0; i < 16; i++) {
            int d_l = i * 4 + hi;
            w1t[((size_t)a * CR + d0 + d_l) * C_DIM + c0 + lo] = f2bf(lds[lo][d_l] * sc);
        }
        __syncthreads();
        if (hi == 0)
            atomicAdd(&bias1[a * CR + d0 + lo], bb[0][lo] + bb[1][lo] + bb[2][lo] + bb[3][lo]);
    } else if (id < 1280) {               // ---- prep_w2t ----
        int id2 = id - 640;
        int k0 = (id2 % 40) * 64, c0 = (id2 / 40) * 64;
        #pragma unroll
        for (int i = 0; i < 16; i++) {
            int k_l = i * 4 + hi;
            lds[k_l][lo] = w2[((size_t)k0 + k_l) * C_DIM + c0 + lo];
        }
        __syncthreads();
        #pragma unroll
        for (int i = 0; i < 16; i++) {
            int c_l = i * 4 + hi;
            w2t[((size_t)c0 + c_l) * KG2 + k0 + lo] = f2bf(lds[lo][c_l]);
        }
    } else if (id < 2304) {               // ---- ln partial sums ----
        int id2 = id - 1280;
        int p0 = (id2 & 63) * 64, c0 = ((id2 >> 6) & 7) * 128, b = id2 >> 9;
        int p = lo, cs = hi;
        float s = 0.f, s2 = 0.f;
        #pragma unroll
        for (int c = cs; c < 128; c += 4) {
            float v = feat[((size_t)b * C_DIM + c0 + c) * HW_N + p0 + p];
            s += v; s2 += v * v;
        }
        float (*sh)[64] = (float(*)[64])lds;
        sh[cs][p] = s; sh[cs + 4][p] = s2;
        __syncthreads();
        if (tid < 64) {
            float ss = sh[0][tid] + sh[1][tid] + sh[2][tid] + sh[3][tid];
            float qq = sh[4][tid] + sh[5][tid] + sh[6][tid] + sh[7][tid];
            int t = b * HW_N + p0 + tid;
            atomicAdd(&sumv[t], ss);
            atomicAdd(&sumq[t], qq);
        }
    } else {                              // ---- wsel compaction + tokmap ----
        if (tid < A_N) { lcnt[tid] = 0; lpos[tid] = 0; }
        __syncthreads();
        int t = (id - 2304) * 256 + tid;  // < 8192
        int b = t >> 12, p = t & (HW_N - 1);
        const float THR[9] = {1.0f/9.0f, 1.0f/7.0f, 0.2f, 1.0f/3.0f, 1.0f, 3.0f, 5.0f, 7.0f, 9.0f};
        int idxs[NANCH];
        #pragma unroll
        for (int na = 0; na < NANCH; na++) {
            float v = ar[(size_t)b * NANCH * HW_N + na * HW_N + p];
            int idx = 0;
            #pragma unroll
            for (int i = 0; i < 9; i++) idx += (v > THR[i]) ? 1 : 0;
            idxs[na] = idx;
        }
        int myA[NANCH], myC[NANCH], nmine = 0;
        #pragma unroll
        for (int j = 0; j < NANCH; j++) {
            bool first = true; int c3 = 0;
            #pragma unroll
            for (int k = 0; k < NANCH; k++) {
                if (idxs[k] == idxs[j]) { c3++; if (k < j) first = false; }
            }
            if (first) {
                myA[nmine] = idxs[j];
                myC[nmine] = c3;
                nmine++;
                atomicAdd(&lcnt[idxs[j]], 1);
            }
        }
        __syncthreads();
        if (tid < A_N) gbase[tid] = atomicAdd(&cnt[tid], lcnt[tid]);
        __syncthreads();
        for (int i = 0; i < NANCH; i++) {
            if (i < nmine) {
                int a2 = myA[i];
                int slot = atomicAdd(&lpos[a2], 1);
                int pos = gbase[a2] + slot;                 // global pos in adapter list
                tokw[a2 * NTOK + pos] = t;                  // row gather for gemm1c
                tokmap[t * 3 + i] = pos | (a2 << 13) | (myC[i] << 17);
            } else {
                tokmap[t * 3 + i] = 0;                      // weight 0 -> ignored
            }
        }
    }
}

// normG[t][c] = bf16((feat - mean)*rstd), token-major; finalizes LN stats inline
__global__ __launch_bounds__(256) void normk(const float* __restrict__ feat,
                                             const float* __restrict__ sumv,
                                             const float* __restrict__ sumq,
                                             ushort_t* __restrict__ normG) {
    int p0 = blockIdx.x * 64, c0 = blockIdx.y * 64, b = blockIdx.z;
    __shared__ float lds[64][65];
    int tid = threadIdx.x, lo = tid & 63, hi = tid >> 6;
    #pragma unroll
    for (int i = 0; i < 16; i++) {
        int c_l = i * 4 + hi;
        lds[c_l][lo] = feat[((size_t)b * C_DIM + c0 + c_l) * HW_N + p0 + lo];
    }
    __syncthreads();
    #pragma unroll
    for (int i = 0; i < 16; i++) {
        int p_l = i * 4 + hi;
        int t = b * HW_N + p0 + p_l;
        float m = sumv[t] * (1.f / C_DIM);
        float q = sumq[t] * (1.f / C_DIM);
        float r = rsqrtf(q - m * m + 1e-5f);
        normG[(size_t)t * C_DIM + c0 + lo] = f2bf((lds[lo][p_l] - m) * r);
    }
}

// ======== 128x128 bf16 MFMA core, pointer-parameterized (XOR-swizzled LDS) ========
__device__ __forceinline__ void gemm_core_ptrs(
    const ushort_t* const ap[4], const ushort_t* const bp[4],
    int K, ushort_t* As, ushort_t* Bs, f32x4 acc[4][4]) {
    const int tid = threadIdx.x;
    const int lane = tid & 63;
    const int w = tid >> 6;
    const int wr = w >> 1, wc = w & 1;
    const int lrow = lane & 15;
    const int quad = lane >> 4;
    const int swzr = lrow & 7;

    #pragma unroll
    for (int i = 0; i < 4; i++)
        #pragma unroll
        for (int j = 0; j < 4; j++)
            #pragma unroll
            for (int e = 0; e < 4; e++) acc[i][j][e] = 0.f;

    for (int k0 = 0; k0 < K; k0 += 64) {
        __syncthreads();
        #pragma unroll
        for (int i = 0; i < 4; i++) {
            __builtin_amdgcn_global_load_lds(
                (__attribute__((address_space(1))) void*)(ap[i] + k0),
                (__attribute__((address_space(3))) void*)(As + (w * 32 + i * 8) * 64),
                16, 0, 0);
            __builtin_amdgcn_global_load_lds(
                (__attribute__((address_space(1))) void*)(bp[i] + k0),
                (__attribute__((address_space(3))) void*)(Bs + (w * 32 + i * 8) * 64),
                16, 0, 0);
        }
        __syncthreads();
        #pragma unroll
        for (int ks = 0; ks < 2; ks++) {
            const int cidx = ((ks * 4 + quad) ^ swzr) * 8;
            bf16x8 af[4], bfr[4];
            #pragma unroll
            for (int mt = 0; mt < 4; mt++)
                af[mt] = *(const bf16x8*)(As + (wr * 64 + mt * 16 + lrow) * 64 + cidx);
            #pragma unroll
            for (int nt = 0; nt < 4; nt++)
                bfr[nt] = *(const bf16x8*)(Bs + (wc * 64 + nt * 16 + lrow) * 64 + cidx);
            #pragma unroll
            for (int mt = 0; mt < 4; mt++)
                #pragma unroll
                for (int nt = 0; nt < 4; nt++)
                    acc[mt][nt] = __builtin_amdgcn_mfma_f32_16x16x32_bf16(af[mt], bfr[nt], acc[mt][nt], 0, 0, 0);
        }
    }
}

// GEMM1 (compacted M): Hc[base_a + i][d] = gelu(norm[tok_i] @ w1'[a] + bias1[a])
__global__ __launch_bounds__(256) void gemm1c(const ushort_t* __restrict__ normG,
                                              const ushort_t* __restrict__ w1t,
                                              const float* __restrict__ bias1,
                                              const int* __restrict__ tokw,
                                              const int* __restrict__ cnt,
                                              ushort_t* __restrict__ Hc) {
    int a = blockIdx.z;
    int mcount = cnt[a];
    int m0 = blockIdx.y * 128;
    if (m0 >= mcount) return;
    int n0 = blockIdx.x * 128;
    int base = 0;
    for (int a2 = 0; a2 < a; a2++) base += cnt[a2];

    __shared__ __align__(16) ushort_t As[128 * 64];
    __shared__ __align__(16) ushort_t Bs[128 * 64];

    int tid = threadIdx.x, lane = tid & 63, w = tid >> 6;
    int lrow8 = lane >> 3;
    int scol = ((lane & 7) ^ lrow8) * 8;
    int srowl = w * 32 + lrow8;

    const ushort_t* ap[4];
    const ushort_t* bp[4];
    #pragma unroll
    for (int i = 0; i < 4; i++) {
        int rt = tokw[a * NTOK + m0 + srowl + i * 8] & (NTOK - 1);
        ap[i] = normG + (size_t)rt * C_DIM + scol;
        bp[i] = w1t + ((size_t)a * CR + n0 + srowl + i * 8) * C_DIM + scol;
    }

    f32x4 acc[4][4];
    gemm_core_ptrs(ap, bp, C_DIM, As, Bs, acc);

    int wr = w >> 1, wc = w & 1, lrow = lane & 15, quad = lane >> 4;
    float bi[4];
    #pragma unroll
    for (int nt = 0; nt < 4; nt++)
        bi[nt] = bias1[a * CR + n0 + wc * 64 + nt * 16 + lrow];
    #pragma unroll
    for (int mt = 0; mt < 4; mt++)
        #pragma unroll
        for (int r = 0; r < 4; r++) {
            int i_row = m0 + wr * 64 + mt * 16 + quad * 4 + r;
            bool live = i_row < mcount;
            #pragma unroll
            for (int nt = 0; nt < 4; nt++) {
                int col = n0 + wc * 64 + nt * 16 + lrow;
                float v = acc[mt][nt][r] + bi[nt];
                if (live)
                    Hc[(size_t)(base + i_row) * CR + col] = f2bf(fast_gelu(v));
            }
        }
}

// GEMM2 (compacted, per-adapter K=256): O[base_a + i][c] = Hc_a[i] @ w2[a]
// 13 GF vs the old dense 43 GF (G was ~78% structural zeros).
__global__ __launch_bounds__(256) void gemm2c(const ushort_t* __restrict__ Hc,
                                              const ushort_t* __restrict__ w2t,
                                              const int* __restrict__ cnt,
                                              ushort_t* __restrict__ O) {
    int a = blockIdx.z;
    int mcount = cnt[a];
    int m0 = blockIdx.y * 128;
    if (m0 >= mcount) return;
    int n0 = blockIdx.x * 128;
    int base = 0;
    for (int a2 = 0; a2 < a; a2++) base += cnt[a2];

    __shared__ __align__(16) ushort_t As[128 * 64];
    __shared__ __align__(16) ushort_t Bs[128 * 64];

    int tid = threadIdx.x, lane = tid & 63, w = tid >> 6;
    int lrow8 = lane >> 3;
    int scol = ((lane & 7) ^ lrow8) * 8;
    int srowl = w * 32 + lrow8;

    const ushort_t* ap[4];
    const ushort_t* bp[4];
    #pragma unroll
    for (int i = 0; i < 4; i++) {
        ap[i] = Hc + (size_t)(base + m0 + srowl + i * 8) * CR + scol;
        bp[i] = w2t + (size_t)(n0 + srowl + i * 8) * KG2 + a * CR + scol;
    }

    f32x4 acc[4][4];
    gemm_core_ptrs(ap, bp, CR, As, Bs, acc);

    int wr = w >> 1, wc = w & 1, lrow = lane & 15, quad = lane >> 4;
    #pragma unroll
    for (int mt = 0; mt < 4; mt++)
        #pragma unroll
        for (int r = 0; r < 4; r++) {
            int i_row = m0 + wr * 64 + mt * 16 + quad * 4 + r;
            bool live = i_row < mcount;
            #pragma unroll
            for (int nt = 0; nt < 4; nt++) {
                int col = n0 + wc * 64 + nt * 16 + lrow;
                if (live)
                    O[(size_t)(base + i_row) * C_DIM + col] = f2bf(acc[mt][nt][r]);
            }
        }
}

// final gather: out[b][c][p] = feat + sum_j w_j * O[gpos_j(t)][c]
__global__ __launch_bounds__(256) void finalk2(const ushort_t* __restrict__ O,
                                               const int* __restrict__ tokmap,
                                               const int* __restrict__ cnt,
                                               const float* __restrict__ feat,
                                               float* __restrict__ out) {
    int p0 = blockIdx.x * 64, c0 = blockIdx.y * 64, b = blockIdx.z;
    __shared__ float lds[64][65];
    __shared__ int pbase[A_N];
    int tid = threadIdx.x, lo = tid & 63, hi = tid >> 6;
    if (tid < A_N) {
        int s = 0;
        for (int k = 0; k < tid; k++) s += cnt[k];
        pbase[tid] = s;
    }
    __syncthreads();
    #pragma unroll
    for (int i = 0; i < 16; i++) {
        int tl = i * 4 + hi;
        int t = b * HW_N + p0 + tl;
        float val = 0.f;
        #pragma unroll
        for (int j = 0; j < 3; j++) {
            int e = tokmap[t * 3 + j];
            float wv = (float)(e >> 17) * (1.0f / 3.0f);
            int a2 = (e >> 13) & 15;
            int row = pbase[a2] + (e & 8191);
            val += wv * bf2f(O[(size_t)row * C_DIM + c0 + lo]);
        }
        lds[tl][lo] = val;
    }
    __syncthreads();
    #pragma unroll
    for (int i = 0; i < 16; i++) {
        int c_l = i * 4 + hi;
        size_t o = ((size_t)b * C_DIM + c0 + c_l) * HW_N + p0 + lo;
        out[o] = lds[lo][c_l] + feat[o];
    }
}

// ---------------- launch ----------------
extern "C" void kernel_launch(void* const* d_in, const int* in_sizes, int n_in,
                              void* d_out, int out_size, void* d_ws, size_t ws_size,
                              hipStream_t stream) {
    (void)in_sizes; (void)n_in; (void)out_size; (void)ws_size;
    const float* feat = (const float*)d_in[0];
    const float* ar   = (const float*)d_in[1];
    const float* ln_s = (const float*)d_in[2];
    const float* ln_b = (const float*)d_in[3];
    const float* w1   = (const float*)d_in[4];
    const float* w2   = (const float*)d_in[5];
    float* out = (float*)d_out;
    char* ws = (char*)d_ws;

    // ---- zero-init region (one small memset: atomic targets only) ----
    float*    bias1  = (float*)(ws + 0);          // 10,240
    int*      cnt    = (int*)(ws + 10240);        // 40 (pad to 10496)
    float*    sumv   = (float*)(ws + 10496);      // 32,768
    float*    sumq   = (float*)(ws + 43264);      // 32,768 (ends 76,032; pad 76,800)
    const size_t ZERO_BYTES = 76800;
    // ---- uninitialized region ----
    int*      tokmap = (int*)(ws + 76800);        // 98,304   -> 175,104
    int*      tokw   = (int*)(ws + 175104);       // 327,680  -> 502,784
    ushort_t* w1t    = (ushort_t*)(ws + 502784);  // 5,242,880 -> 5,745,664
    ushort_t* w2t    = (ushort_t*)(ws + 5745664); // 5,242,880 -> 10,988,544
    ushort_t* normG  = (ushort_t*)(ws + 10988544);// 16,777,216 -> 27,765,760
    ushort_t* Hc     = (ushort_t*)(ws + 27765760);// (24576+128)*256*2 = 12,648,448 -> 40,414,208
    ushort_t* O      = (ushort_t*)(ws + 40414208);// 24576*1024*2 = 50,331,648 -> 90,745,856

    dim3 blk(256);
    hipMemsetAsync(ws, 0, ZERO_BYTES, stream);
    prep_all<<<dim3(2336), blk, 0, stream>>>(w1, w2, ln_s, ln_b, feat, ar,
                                             w1t, w2t, bias1, sumv, sumq, cnt, tokw, tokmap);
    normk<<<dim3(64, 16, B_N), blk, 0, stream>>>(feat, sumv, sumq, normG);
    gemm1c<<<dim3(2, 64, A_N), blk, 0, stream>>>(normG, w1t, bias1, tokw, cnt, Hc);
    gemm2c<<<dim3(8, 64, A_N), blk, 0, stream>>>(Hc, w2t, cnt, O);
    finalk2<<<dim3(64, 16, B_N), blk, 0, stream>>>(O, tokmap, cnt, feat, out);
}